// Round 10
// baseline (4136.925 us; speedup 1.0000x reference)
//
#include <hip/hip_runtime.h>
#include <cstdint>
#include <cstddef>

// LSTM_Generator: 3-layer LSTM (H=100) + tanh projection. B=512, T=512, fp32.
//
// R9. Allocator model from R0-R8: unified VGPR+AGPR budget 128/thread at
// (4,4); live set ~125+ -> blunt 64/64 VGPR/AGPR collapse (1 extra VALU per
// weight access, 2-3x step cost). Fix: engineer gate-thread live set to ~105:
//  - helper wave (tid>=448): prefetches xw(s+1)/z(s+1) -> LDS dbuf, writes
//    h(s-1) back to global. Gate threads hold NO global pointers in-loop.
//  - weight tail: w[0..87] in regs, w[88..99] in transposed LDS wtail[12][400]
//    (12 conflict-free volatile b32 reads/step; volatile blocks LICM).
// Non-template rec kernels; chunk len TLEN=128 compile-time.
// Structure: per layer, chunked [tiled xw_gemm -> recx]; layer0 = rec0 full-T.
// ws: hbuf[NB*NT*HH] | cbuf[NB*HH] | wt1[HH*448] | wt2 | bp1[448] | bp2 | xw[NB*TLEN*G4]

#define HH 100   // hidden
#define G4 400   // 4*H
#define NB 512   // batch
#define NT 512   // timesteps
#define TLEN 128 // rec chunk length
#define KREG 88  // weights in registers
#define KTL 12   // weights in LDS tail
#define WSTR 448 // padded gate dim for wT/bperm
#define MT 64    // GEMM M tile
#define NTL 64   // GEMM N tile
#define NNT 7    // ceil(400/64)

#define PIN44 __attribute__((amdgpu_flat_work_group_size(512, 512), \
                             amdgpu_waves_per_eu(4, 4)))
#define PIN22 __attribute__((amdgpu_flat_work_group_size(512, 512), \
                             amdgpu_waves_per_eu(2, 2)))

__device__ __forceinline__ float sigm(float x) {
  return 1.0f / (1.0f + __expf(-x));
}
__device__ __forceinline__ float tanh_(float x) {
  return 1.0f - 2.0f / (__expf(2.0f * x) + 1.0f);
}
__device__ __forceinline__ float qb1(float v) {
  return __int_as_float(__builtin_amdgcn_ds_swizzle(__float_as_int(v), 0x8055));
}
__device__ __forceinline__ float qb2(float v) {
  return __int_as_float(__builtin_amdgcn_ds_swizzle(__float_as_int(v), 0x80AA));
}
__device__ __forceinline__ float qb3(float v) {
  return __int_as_float(__builtin_amdgcn_ds_swizzle(__float_as_int(v), 0x80FF));
}

// gate-thread inner dot: 88 reg weights + 12 LDS-tail weights
__device__ __forceinline__ float gate_dot(const float* __restrict__ hbuf_lds,
                                          const float w[KREG],
                                          volatile const float* wt) {
  const float4* h4 = reinterpret_cast<const float4*>(hbuf_lds);
  float a0 = 0.f, a1 = 0.f, a2 = 0.f, a3 = 0.f;
#pragma unroll
  for (int k = 0; k < KREG / 4; ++k) {
    float4 v = h4[k];                    // uniform address -> broadcast
    a0 += v.x * w[4 * k];     a1 += v.y * w[4 * k + 1];
    a2 += v.z * w[4 * k + 2]; a3 += v.w * w[4 * k + 3];
  }
  float4 t0 = h4[22], t1 = h4[23], t2 = h4[24];   // h[88..99]
  a0 += t0.x * wt[0 * G4];  a1 += t0.y * wt[1 * G4];
  a2 += t0.z * wt[2 * G4];  a3 += t0.w * wt[3 * G4];
  a0 += t1.x * wt[4 * G4];  a1 += t1.y * wt[5 * G4];
  a2 += t1.z * wt[6 * G4];  a3 += t1.w * wt[7 * G4];
  a0 += t2.x * wt[8 * G4];  a1 += t2.y * wt[9 * G4];
  a2 += t2.z * wt[10 * G4]; a3 += t2.w * wt[11 * G4];
  return (a0 + a1) + (a2 + a3);
}

// ---------------- layer 0: K=1 scalar input, full length ----------------
__global__ PIN44 void rec0(
    const float* __restrict__ z,      // [NB, NT]
    const float* __restrict__ Wih,    // [G4, 1]
    const float* __restrict__ Whh,    // [G4, HH]
    const float* __restrict__ bias,   // [G4]
    float* __restrict__ hseq)         // [NB, NT, HH]
{
  const int b = blockIdx.x;
  const int tid = threadIdx.x;

  __shared__ __align__(16) float h_lds[2][HH];
  __shared__ __align__(16) float z_lds[2];
  __shared__ __align__(16) float wtail[KTL][G4];

  const bool isG = tid < G4;
  const int u = tid >> 2, g = tid & 3;
  const int row = g * HH + u;

  float w[KREG];
  float bb = 0.f, wih1 = 0.f, c = 0.f;
  if (isG) {
    const float4* w4 = reinterpret_cast<const float4*>(Whh + (size_t)row * HH);
#pragma unroll
    for (int k = 0; k < KREG / 4; ++k) {
      float4 v = w4[k];
      w[4 * k] = v.x; w[4 * k + 1] = v.y; w[4 * k + 2] = v.z; w[4 * k + 3] = v.w;
    }
#pragma unroll
    for (int j = 0; j < KTL; ++j)
      wtail[j][tid] = Whh[(size_t)row * HH + KREG + j];
    wih1 = Wih[row];
    bb = bias[row];
  }
  if (tid < HH) h_lds[0][tid] = 0.0f;

  const float* zb = z + (size_t)b * NT;
  float* hb = hseq + (size_t)b * NT * HH;
  if (tid == 448) z_lds[0] = zb[0];
  volatile const float* wt = &wtail[0][0] + tid;
  __syncthreads();

  for (int s = 0; s < NT; ++s) {
    const int cur = s & 1, nxt = cur ^ 1;
    if (isG) {
      float zc = z_lds[cur];
      float acc = bb + wih1 * zc + gate_dot(h_lds[cur], w, wt);
      float act = (g == 2) ? tanh_(acc) : sigm(acc);
      float fv = qb1(act);
      float gv = qb2(act);
      float ov = qb3(act);
      if (g == 0) {                          // lane 4u owns unit u's c,h
        c = fv * c + act * gv;
        h_lds[nxt][u] = ov * tanh_(c);
      }
    } else if (tid >= 448) {
      const int q = tid - 448;
      if (q == 0) {
        int sn = (s + 1 < NT) ? s + 1 : NT - 1;
        z_lds[nxt] = zb[sn];
      }
      if (q < 25 && s > 0) {                 // write back h(s-1)
        reinterpret_cast<float4*>(hb + (size_t)(s - 1) * HH)[q] =
            reinterpret_cast<const float4*>(h_lds[cur])[q];
      }
    }
    __syncthreads();
  }
  // final h row (s=NT-1) sits in h_lds[NT&1 == 0]
  if (tid >= 448 && tid < 448 + 25) {
    reinterpret_cast<float4*>(hb + (size_t)(NT - 1) * HH)[tid - 448] =
        reinterpret_cast<const float4*>(h_lds[0])[tid - 448];
  }
}

// ---------------- chunk recurrence: xw precomputed (bias folded) ----------
__global__ PIN44 void recx(
    const float* __restrict__ xw,     // [NB, TLEN, G4], quad-permuted cols
    const float* __restrict__ Whh,    // [G4, HH]
    float* __restrict__ hseq,         // [NB, NT, HH]
    float* __restrict__ cbuf,         // [NB, HH]
    int t0)
{
  const int b = blockIdx.x;
  const int tid = threadIdx.x;

  __shared__ __align__(16) float h_lds[2][HH];
  __shared__ __align__(16) float xw_lds[2][G4];
  __shared__ __align__(16) float wtail[KTL][G4];

  const bool isG = tid < G4;
  const int u = tid >> 2, g = tid & 3;
  const int row = g * HH + u;

  float w[KREG];
  float c = 0.f;
  if (isG) {
    const float4* w4 = reinterpret_cast<const float4*>(Whh + (size_t)row * HH);
#pragma unroll
    for (int k = 0; k < KREG / 4; ++k) {
      float4 v = w4[k];
      w[4 * k] = v.x; w[4 * k + 1] = v.y; w[4 * k + 2] = v.z; w[4 * k + 3] = v.w;
    }
#pragma unroll
    for (int j = 0; j < KTL; ++j)
      wtail[j][tid] = Whh[(size_t)row * HH + KREG + j];
  }

  // chunk init: h(t0-1), c
  if (t0 == 0) {
    if (tid < HH) h_lds[0][tid] = 0.0f;
  } else {
    if (tid < 25)
      reinterpret_cast<float4*>(h_lds[0])[tid] =
          reinterpret_cast<const float4*>(
              hseq + ((size_t)b * NT + (t0 - 1)) * HH)[tid];
    if (isG && g == 0) c = cbuf[b * HH + u];
  }

  const float* xwb = xw + (size_t)b * TLEN * G4;
  float* hb = hseq + ((size_t)b * NT + t0) * HH;

  // helper-wave prologue: xw(0) -> xw_lds[0]
  if (tid >= 448) {
    const int q = tid - 448;
    const float4* x4 = reinterpret_cast<const float4*>(xwb);
    if (q < 100) reinterpret_cast<float4*>(xw_lds[0])[q] = x4[q];
    const int q2 = q + 64;
    if (q2 < 100) reinterpret_cast<float4*>(xw_lds[0])[q2] = x4[q2];
  }
  volatile const float* wt = &wtail[0][0] + tid;
  __syncthreads();

  for (int s = 0; s < TLEN; ++s) {
    const int cur = s & 1, nxt = cur ^ 1;
    if (isG) {
      float acc = xw_lds[cur][tid] + gate_dot(h_lds[cur], w, wt);
      float act = (g == 2) ? tanh_(acc) : sigm(acc);
      float fv = qb1(act);
      float gv = qb2(act);
      float ov = qb3(act);
      if (g == 0) {
        c = fv * c + act * gv;
        h_lds[nxt][u] = ov * tanh_(c);
      }
    } else if (tid >= 448) {
      const int q = tid - 448;
      const int sn = (s + 1 < TLEN) ? s + 1 : TLEN - 1;
      const float4* x4 = reinterpret_cast<const float4*>(xwb + (size_t)sn * G4);
      if (q < 100) reinterpret_cast<float4*>(xw_lds[nxt])[q] = x4[q];
      const int q2 = q + 64;
      if (q2 < 100) reinterpret_cast<float4*>(xw_lds[nxt])[q2] = x4[q2];
      if (q < 25 && (s + t0 > 0)) {          // write back h(t0+s-1)
        reinterpret_cast<float4*>(hb + (size_t)(s - 1) * HH)[q] =
            reinterpret_cast<const float4*>(h_lds[cur])[q];
      }
    }
    __syncthreads();
  }
  if (isG && g == 0) cbuf[b * HH + u] = c;
  // final row t0+TLEN-1 sits in h_lds[TLEN&1 == 0]
  if (tid >= 448 && tid < 448 + 25) {
    reinterpret_cast<float4*>(hb + (size_t)(TLEN - 1) * HH)[tid - 448] =
        reinterpret_cast<const float4*>(h_lds[0])[tid - 448];
  }
}

// ---------------- weight prep: wT[k][n] = Wih[perm(n)][k], bias permuted ----
__global__ __launch_bounds__(256) void wprep(
    const float* __restrict__ Wih,   // [G4, HH]
    const float* __restrict__ bias,  // [G4]
    float* __restrict__ wT,          // [HH, WSTR]
    float* __restrict__ bp)          // [WSTR]
{
  int idx = blockIdx.x * blockDim.x + threadIdx.x;
  if (idx >= HH * WSTR) return;
  int k = idx / WSTR, n = idx % WSTR;
  float v = 0.0f;
  if (n < G4) {
    int row = (n & 3) * HH + (n >> 2);      // quad map: n=4u+g -> row g*H+u
    v = Wih[(size_t)row * HH + k];
  }
  wT[idx] = v;
  if (idx < WSTR) bp[idx] = (idx < G4) ? bias[(idx & 3) * HH + (idx >> 2)] : 0.0f;
}

// ---------------- input GEMM: xw[b][t][n] = bperm[n] + h[b][t0+t][:].wT[:][n]
__global__ __launch_bounds__(256) void xw_gemm(
    const float* __restrict__ hsrc,  // [NB, NT, HH]
    const float* __restrict__ wT,    // [HH, WSTR]
    const float* __restrict__ bperm, // [WSTR]
    float* __restrict__ xw,          // [NB, TLEN, G4]
    int t0)
{
  const int mt = blockIdx.x / NNT, nt = blockIdx.x % NNT;
  const int m0 = mt * MT;
  const int b = m0 / TLEN, tr0 = m0 % TLEN;
  const int n0 = nt * NTL;
  const int tid = threadIdx.x;
  const int tx = tid & 15, ty = tid >> 4;

  __shared__ float Asub[HH][MT];
  __shared__ float Bsub[HH][NTL];

  for (int id = tid; id < MT * (HH / 4); id += 256) {
    const int k4 = id / MT, i = id % MT;
    const float4 v = *reinterpret_cast<const float4*>(
        hsrc + ((size_t)b * NT + (t0 + tr0 + i)) * HH + 4 * k4);
    Asub[4 * k4 + 0][i] = v.x;
    Asub[4 * k4 + 1][i] = v.y;
    Asub[4 * k4 + 2][i] = v.z;
    Asub[4 * k4 + 3][i] = v.w;
  }
  for (int id = tid; id < HH * (NTL / 4); id += 256) {
    const int k = id / (NTL / 4), q = id % (NTL / 4);
    const float4 v = *reinterpret_cast<const float4*>(wT + (size_t)k * WSTR + n0 + 4 * q);
    *reinterpret_cast<float4*>(&Bsub[k][4 * q]) = v;
  }
  __syncthreads();

  float acc[4][4] = {};
#pragma unroll 4
  for (int k = 0; k < HH; ++k) {
    const float4 a = *reinterpret_cast<const float4*>(&Asub[k][4 * ty]);
    const float4 bq = *reinterpret_cast<const float4*>(&Bsub[k][4 * tx]);
    acc[0][0] += a.x * bq.x; acc[0][1] += a.x * bq.y; acc[0][2] += a.x * bq.z; acc[0][3] += a.x * bq.w;
    acc[1][0] += a.y * bq.x; acc[1][1] += a.y * bq.y; acc[1][2] += a.y * bq.z; acc[1][3] += a.y * bq.w;
    acc[2][0] += a.z * bq.x; acc[2][1] += a.z * bq.y; acc[2][2] += a.z * bq.z; acc[2][3] += a.z * bq.w;
    acc[3][0] += a.w * bq.x; acc[3][1] += a.w * bq.y; acc[3][2] += a.w * bq.z; acc[3][3] += a.w * bq.w;
  }

  const int n = n0 + 4 * tx;
  if (n + 3 < G4) {
    const float4 bpq = *reinterpret_cast<const float4*>(bperm + n);
#pragma unroll
    for (int jr = 0; jr < 4; ++jr) {
      float4 o;
      o.x = acc[jr][0] + bpq.x; o.y = acc[jr][1] + bpq.y;
      o.z = acc[jr][2] + bpq.z; o.w = acc[jr][3] + bpq.w;
      *reinterpret_cast<float4*>(
          &xw[((size_t)b * TLEN + tr0 + 4 * ty + jr) * G4 + n]) = o;
    }
  }
}

// ---------------- fallback fused layer (only if ws too small) --------------
__global__ PIN22 void lstm_fused(
    const float* x,
    const float* __restrict__ Wih,
    const float* __restrict__ Whh,
    const float* __restrict__ bias,
    float* hseq)
{
  const int b = blockIdx.x;
  const int tid = threadIdx.x;
  __shared__ __align__(16) float h_dbuf[2][HH];
  __shared__ __align__(16) float x_dbuf[2][HH];
  const bool isG = tid < G4;
  const int u = tid >> 2, g = tid & 3;
  const int row = g * HH + u;
  float whh[HH], wih[HH];
  float bb = 0.f, c = 0.f;
  if (isG) {
    const float4* wh4 = reinterpret_cast<const float4*>(Whh + (size_t)row * HH);
    const float4* wi4 = reinterpret_cast<const float4*>(Wih + (size_t)row * HH);
#pragma unroll
    for (int k = 0; k < HH / 4; ++k) {
      float4 a = wh4[k];
      whh[4 * k] = a.x; whh[4 * k + 1] = a.y; whh[4 * k + 2] = a.z; whh[4 * k + 3] = a.w;
      float4 bq = wi4[k];
      wih[4 * k] = bq.x; wih[4 * k + 1] = bq.y; wih[4 * k + 2] = bq.z; wih[4 * k + 3] = bq.w;
    }
    bb = bias[row];
  }
  if (tid < HH) h_dbuf[0][tid] = 0.0f;
  const float* xb = x + (size_t)b * NT * HH;
  float* hb = hseq + (size_t)b * NT * HH;
  const unsigned pf = (unsigned)(tid - 448);
  if (pf < 25u)
    reinterpret_cast<float4*>(x_dbuf[0])[pf] = reinterpret_cast<const float4*>(xb)[pf];
  __syncthreads();
  for (int t = 0; t < NT; ++t) {
    const int cur = t & 1, nxt = cur ^ 1;
    if (pf < 25u) {
      int tt = (t + 1 < NT) ? t + 1 : NT - 1;
      reinterpret_cast<float4*>(x_dbuf[nxt])[pf] =
          reinterpret_cast<const float4*>(xb + (size_t)tt * HH)[pf];
    }
    if (isG) {
      float a0 = 0.f, a1 = 0.f, a2 = 0.f, a3 = 0.f;
      const float4* x4 = reinterpret_cast<const float4*>(x_dbuf[cur]);
      const float4* h4 = reinterpret_cast<const float4*>(h_dbuf[cur]);
#pragma unroll
      for (int k = 0; k < HH / 4; ++k) {
        float4 v = x4[k];
        a0 += v.x * wih[4 * k];     a1 += v.y * wih[4 * k + 1];
        a2 += v.z * wih[4 * k + 2]; a3 += v.w * wih[4 * k + 3];
      }
#pragma unroll
      for (int k = 0; k < HH / 4; ++k) {
        float4 v = h4[k];
        a0 += v.x * whh[4 * k];     a1 += v.y * whh[4 * k + 1];
        a2 += v.z * whh[4 * k + 2]; a3 += v.w * whh[4 * k + 3];
      }
      float acc = bb + ((a0 + a1) + (a2 + a3));
      float act = (g == 2) ? tanh_(acc) : sigm(acc);
      float fv = qb1(act);
      float gv = qb2(act);
      float ov = qb3(act);
      if (g == 0) {
        c = fv * c + act * gv;
        float hv = ov * tanh_(c);
        h_dbuf[nxt][u] = hv;
        hb[(size_t)t * HH + u] = hv;
      }
    }
    __syncthreads();
  }
}

// ---------------- projection ----------------
__global__ __launch_bounds__(256) void proj_kernel(
    const float* __restrict__ hseq,
    const float* __restrict__ Wp,
    const float* __restrict__ bp,
    float* __restrict__ out)
{
  int idx = blockIdx.x * blockDim.x + threadIdx.x;
  if (idx >= NB * NT) return;
  const float4* h4 = reinterpret_cast<const float4*>(hseq + (size_t)idx * HH);
  const float4* w4 = reinterpret_cast<const float4*>(Wp);
  float a0 = 0.f, a1 = 0.f, a2 = 0.f, a3 = 0.f;
#pragma unroll
  for (int k = 0; k < HH / 4; ++k) {
    float4 h = h4[k];
    float4 w = w4[k];
    a0 += h.x * w.x; a1 += h.y * w.y; a2 += h.z * w.z; a3 += h.w * w.w;
  }
  out[idx] = tanh_(((a0 + a1) + (a2 + a3)) + bp[0]);
}

extern "C" void kernel_launch(void* const* d_in, const int* in_sizes, int n_in,
                              void* d_out, int out_size, void* d_ws, size_t ws_size,
                              hipStream_t stream) {
  const float* z    = (const float*)d_in[0];
  const float* Wih0 = (const float*)d_in[1];
  const float* Whh0 = (const float*)d_in[2];
  const float* b0   = (const float*)d_in[3];
  const float* Wih1 = (const float*)d_in[4];
  const float* Whh1 = (const float*)d_in[5];
  const float* b1   = (const float*)d_in[6];
  const float* Wih2 = (const float*)d_in[7];
  const float* Whh2 = (const float*)d_in[8];
  const float* b2   = (const float*)d_in[9];
  const float* Wp   = (const float*)d_in[10];
  const float* bp   = (const float*)d_in[11];
  float* out = (float*)d_out;

  float* hbuf = (float*)d_ws;                       // [NB,NT,HH]
  float* cbuf = hbuf + (size_t)NB * NT * HH;        // [NB,HH]
  float* wt1  = cbuf + (size_t)NB * HH;             // [HH,WSTR]
  float* wt2  = wt1 + (size_t)HH * WSTR;
  float* bp1  = wt2 + (size_t)HH * WSTR;            // [WSTR]
  float* bp2  = bp1 + WSTR;
  float* xwb  = bp2 + WSTR;                         // [NB,TLEN,G4]

  const size_t need = ((size_t)(bp2 + WSTR - hbuf) + (size_t)NB * TLEN * G4) * 4;

  // layer 0 (K=1): full-length
  rec0<<<NB, 512, 0, stream>>>(z, Wih0, Whh0, b0, hbuf);

  if (need <= ws_size) {
    wprep<<<(HH * WSTR + 255) / 256, 256, 0, stream>>>(Wih1, b1, wt1, bp1);
    wprep<<<(HH * WSTR + 255) / 256, 256, 0, stream>>>(Wih2, b2, wt2, bp2);
    const float* wtL[2] = {wt1, wt2};
    const float* bpL[2] = {bp1, bp2};
    const float* WhhL[2] = {Whh1, Whh2};
    const int gemm_grid = (NB * TLEN / MT) * NNT;
    for (int l = 0; l < 2; ++l) {
      for (int t0 = 0; t0 < NT; t0 += TLEN) {
        xw_gemm<<<gemm_grid, 256, 0, stream>>>(hbuf, wtL[l], bpL[l], xwb, t0);
        recx<<<NB, 512, 0, stream>>>(xwb, WhhL[l], hbuf, cbuf, t0);
      }
    }
  } else {
    lstm_fused<<<NB, 512, 0, stream>>>(hbuf, Wih1, Whh1, b1, hbuf);
    lstm_fused<<<NB, 512, 0, stream>>>(hbuf, Wih2, Whh2, b2, hbuf);
  }

  proj_kernel<<<(NB * NT + 255) / 256, 256, 0, stream>>>(hbuf, Wp, bp, out);
}

// Round 11
// 3714.410 us; speedup vs baseline: 1.1138x; 1.1138x over previous
//
#include <hip/hip_runtime.h>
#include <cstdint>
#include <cstddef>

// LSTM_Generator: 3-layer LSTM (H=100) + tanh projection. B=512, T=512.
//
// R10: abandon the VALU broadcast-matvec (10 rounds of register-allocator
// fights, always 64-VGPR collapse). Use MFMA: batch 16 rows per block
// (32 blocks), per step gates^T[400p,16] = Whh_frag[400p,100] @ h^T[100,16]
// via mfma_f32_16x16x32_f16. Precision: W fp16 single, h split fp16 hi+lo
// (2 MFMA passes) ~ fp32-class error. Unit-major row permute m'=4u+g makes
// each lane hold (i,f,g,o) of ONE unit for ONE batch row in its 4 acc regs:
// cell update fully in-lane (C-layout col=lane&15, row=(lane>>4)*4+r, HW-
// verified). A/B packed by wprep with ONE shared k-map (k-permutation
// cancels in the MFMA dot, so the HW's internal k-order doesn't matter).
// xw = bias + Wih.x precomputed per chunk by an MFMA pass (parallel over t).
// hbufT layout [bgrp][t][u][16br] for coalesced writes from C-layout.

#define HH 100
#define G4 400
#define NB 512
#define NT 512
#define BB 16
#define NBG 32
#define NTILE 25
#define KP 168   // padded k extent in LDS fp16 rows (bank-friendly: 336B stride)

typedef _Float16 f16;
typedef _Float16 f16x8 __attribute__((ext_vector_type(8)));
typedef float f32x4 __attribute__((ext_vector_type(4)));

__device__ __forceinline__ float sigm(float x) { return 1.0f / (1.0f + __expf(-x)); }
__device__ __forceinline__ float tanh_(float x) { return 1.0f - 2.0f / (__expf(2.0f * x) + 1.0f); }

#define PIN11 __attribute__((amdgpu_flat_work_group_size(256, 256), \
                             amdgpu_waves_per_eu(1, 1)))
#define PIN22 __attribute__((amdgpu_flat_work_group_size(512, 512), \
                             amdgpu_waves_per_eu(2, 2)))

// ---------------- weight prep: pack MFMA fragments ----------------
// Shared k-map (A and B both): k = kt*32 + (lane>>4)*8 + j, j=0..7.
// A-frag element: m' = nt*16 + (lane&15); orig row = (m'&3)*100 + (m'>>2).
// bias/l0 tables use the C/D map: m' = nt*16 + (lane>>4)*4 + r.
__global__ __launch_bounds__(256) void wprep(
    const float* __restrict__ Whh0, const float* __restrict__ Whh1,
    const float* __restrict__ Whh2, const float* __restrict__ Wih1,
    const float* __restrict__ Wih2, const float* __restrict__ b1,
    const float* __restrict__ b2, const float* __restrict__ Wih0,
    const float* __restrict__ b0,
    f16* __restrict__ wfA, f16* __restrict__ wfI,
    float* __restrict__ biasf, float* __restrict__ l0w, float* __restrict__ l0b)
{
  int idx = blockIdx.x * 256 + threadIdx.x;
  if (idx < 153600) {                        // wfA [3][25][4][64][8] halves
    int l = idx / 51200, r = idx % 51200;
    int nt = r / 2048, r2 = r % 2048;
    int kt = r2 / 512, r3 = r2 % 512;
    int lane = r3 / 8, j = r3 % 8;
    int mp = nt * 16 + (lane & 15);
    int grow = (mp & 3) * HH + (mp >> 2);
    int k = kt * 32 + (lane >> 4) * 8 + j;
    const float* W = (l == 0) ? Whh0 : ((l == 1) ? Whh1 : Whh2);
    wfA[idx] = (k < HH) ? (f16)W[grow * HH + k] : (f16)0.0f;
    return;
  }
  idx -= 153600;
  if (idx < 102400) {                        // wfI [2][25][4][64][8] halves
    int l = idx / 51200, r = idx % 51200;
    int nt = r / 2048, r2 = r % 2048;
    int kt = r2 / 512, r3 = r2 % 512;
    int lane = r3 / 8, j = r3 % 8;
    int mp = nt * 16 + (lane & 15);
    int grow = (mp & 3) * HH + (mp >> 2);
    int k = kt * 32 + (lane >> 4) * 8 + j;
    const float* W = (l == 0) ? Wih1 : Wih2;
    wfI[idx] = (k < HH) ? (f16)W[grow * HH + k] : (f16)0.0f;
    return;
  }
  idx -= 102400;
  if (idx < 12800) {                         // biasf [2][25][64][4] f32
    int l = idx / 6400, r = idx % 6400;
    int nt = r / 256, r2 = r % 256;
    int lane = r2 / 4, rr = r2 % 4;
    int mp = nt * 16 + (lane >> 4) * 4 + rr;
    int grow = (mp & 3) * HH + (mp >> 2);
    biasf[idx] = ((l == 0) ? b1 : b2)[grow];
    return;
  }
  idx -= 12800;
  if (idx < 12800) {                         // l0w / l0b [25][64][4] f32
    int w = idx / 6400, r = idx % 6400;
    int nt = r / 256, r2 = r % 256;
    int lane = r2 / 4, rr = r2 % 4;
    int mp = nt * 16 + (lane >> 4) * 4 + rr;
    int grow = (mp & 3) * HH + (mp >> 2);
    if (w == 0) l0w[r] = Wih0[grow];
    else        l0b[r] = b0[grow];
  }
}

// ---------------- xw pass: xwf = bias + Wih . x^T (MFMA, parallel in t) ----
__global__ PIN22 void xwp(
    const float* __restrict__ hbufT,   // prev layer h: [bg][t][u][16]
    const f16* __restrict__ wfIl,      // [25][4][64][8]
    const float* __restrict__ biasl,   // [25][64][4]
    float* __restrict__ xwf,           // [bg][CT][25][64][4]
    int t0, int CT)
{
  const int tid = threadIdx.x;
  const int w = tid >> 6, lane = tid & 63;
  const int nblk = CT / 8;
  const int bg = blockIdx.x / nblk, ts = blockIdx.x % nblk;
  const int tb = t0 + ts * 8;

  __shared__ f16 x16[8][16][KP];   // 42KB, x as fp16 single

  for (int i = tid; i < 8 * HH * 16; i += 512) {
    int t = i / 1600, r = i % 1600;
    int u = r >> 4, br = r & 15;
    float v = hbufT[(((size_t)bg * NT + (tb + t)) * HH + u) * 16 + br];
    x16[t][br][u] = (f16)v;
  }
  for (int i = tid; i < 8 * 16 * 28; i += 512) {   // zero k in [100,128)
    int t = i / 448, r = i % 448;
    int br = r / 28, k = 100 + r % 28;
    x16[t][br][k] = (f16)0.0f;
  }

  const int NS = (w == 7) ? 4 : 3;
  const int tbase = 3 * w;

  f16x8 A[4][4];
  f32x4 bias4[4];
#pragma unroll
  for (int s = 0; s < 4; ++s) {
    if (s < NS) {
      int nt = tbase + s;
#pragma unroll
      for (int kt = 0; kt < 4; ++kt)
        A[s][kt] = *(const f16x8*)(wfIl + ((nt * 4 + kt) * 64 + lane) * 8);
      bias4[s] = *(const f32x4*)(biasl + (nt * 64 + lane) * 4);
    }
  }
  __syncthreads();

  for (int t = 0; t < 8; ++t) {
    f16x8 B[4];
#pragma unroll
    for (int kt = 0; kt < 4; ++kt)
      B[kt] = *(const f16x8*)(&x16[t][lane & 15][kt * 32 + (lane >> 4) * 8]);
    const int tc = ts * 8 + t;
#pragma unroll
    for (int s = 0; s < 4; ++s) {
      if (s < NS) {
        f32x4 acc = bias4[s];
#pragma unroll
        for (int kt = 0; kt < 4; ++kt)
          acc = __builtin_amdgcn_mfma_f32_16x16x32_f16(A[s][kt], B[kt], acc, 0, 0, 0);
        int nt = tbase + s;
        *(f32x4*)(xwf + ((((size_t)bg * CT + tc) * NTILE + nt) * 64 + lane) * 4) = acc;
      }
    }
  }
}

// ---------------- recurrent kernel, layers 1/2 ----------------
// 256 thr = 4 waves; slot s of wave w -> tile nt = s*4 + w (guard nt<25):
// waves get {7,6,6,6} tiles, uniform code, compile-time slot indices.
__global__ PIN11 void recx(
    const float* __restrict__ xwf,
    const f16* __restrict__ wfAl,
    float* __restrict__ hbufT,
    float* __restrict__ cbuf,
    int t0, int CT)
{
  const int tid = threadIdx.x;
  const int w = tid >> 6, lane = tid & 63;
  const int bg = blockIdx.x;
  const int br = lane & 15, lg = lane >> 4;

  __shared__ f16 hHi[16][KP];
  __shared__ f16 hLo[16][KP];

  for (int i = tid; i < 16 * KP; i += 256) {       // zero all (incl. pad)
    int b = i / KP, k = i % KP;
    hHi[b][k] = (f16)0.0f;
    hLo[b][k] = (f16)0.0f;
  }
  __syncthreads();
  if (t0 > 0) {
    for (int i = tid; i < HH * 16; i += 256) {
      int u = i >> 4, bb = i & 15;
      float v = hbufT[(((size_t)bg * NT + (t0 - 1)) * HH + u) * 16 + bb];
      f16 hi = (f16)v;
      hHi[bb][u] = hi;
      hLo[bb][u] = (f16)(v - (float)hi);
    }
  }

  f16x8 A[7][4];
  float c[7];
  f32x4 xwC[7], xwN[7];
#pragma unroll
  for (int s = 0; s < 7; ++s) {
    const int nt = s * 4 + w;
    if (nt < NTILE) {
#pragma unroll
      for (int kt = 0; kt < 4; ++kt)
        A[s][kt] = *(const f16x8*)(wfAl + ((nt * 4 + kt) * 64 + lane) * 8);
      c[s] = (t0 > 0) ? cbuf[((size_t)bg * NTILE + nt) * 64 + lane] : 0.0f;
      xwC[s] = *(const f32x4*)(xwf + (((size_t)bg * CT * NTILE + nt) * 64 + lane) * 4);
    }
  }
  __syncthreads();

  for (int t = 0; t < CT; ++t) {
    f16x8 Bhi[4], Blo[4];
#pragma unroll
    for (int kt = 0; kt < 4; ++kt) {
      Bhi[kt] = *(const f16x8*)(&hHi[br][kt * 32 + lg * 8]);
      Blo[kt] = *(const f16x8*)(&hLo[br][kt * 32 + lg * 8]);
    }
    const int tn = (t + 1 < CT) ? t + 1 : t;       // prefetch next xw
#pragma unroll
    for (int s = 0; s < 7; ++s) {
      const int nt = s * 4 + w;
      if (nt < NTILE)
        xwN[s] = *(const f32x4*)(xwf + ((((size_t)bg * CT + tn) * NTILE + nt) * 64 + lane) * 4);
    }
    f16 hhi[7], hlo[7];
#pragma unroll
    for (int s = 0; s < 7; ++s) {
      const int nt = s * 4 + w;
      if (nt < NTILE) {
        f32x4 acc = xwC[s];
#pragma unroll
        for (int kt = 0; kt < 4; ++kt) {
          acc = __builtin_amdgcn_mfma_f32_16x16x32_f16(A[s][kt], Bhi[kt], acc, 0, 0, 0);
          acc = __builtin_amdgcn_mfma_f32_16x16x32_f16(A[s][kt], Blo[kt], acc, 0, 0, 0);
        }
        float iv = sigm(acc.x);
        float fv = sigm(acc.y);
        float gv = tanh_(acc.z);
        float ov = sigm(acc.w);
        c[s] = fv * c[s] + iv * gv;
        float hv = ov * tanh_(c[s]);
        f16 hi = (f16)hv;
        hhi[s] = hi;
        hlo[s] = (f16)(hv - (float)hi);
        const int u = nt * 4 + lg;
        hbufT[(((size_t)bg * NT + (t0 + t)) * HH + u) * 16 + br] = hv;
      }
    }
    __syncthreads();                               // all h_lds reads done
#pragma unroll
    for (int s = 0; s < 7; ++s) {
      const int nt = s * 4 + w;
      if (nt < NTILE) {
        const int u = nt * 4 + lg;
        hHi[br][u] = hhi[s];
        hLo[br][u] = hlo[s];
      }
    }
#pragma unroll
    for (int s = 0; s < 7; ++s) xwC[s] = xwN[s];
    __syncthreads();                               // writes visible
  }
#pragma unroll
  for (int s = 0; s < 7; ++s) {
    const int nt = s * 4 + w;
    if (nt < NTILE) cbuf[((size_t)bg * NTILE + nt) * 64 + lane] = c[s];
  }
}

// ---------------- layer 0 (K=1 scalar input), full T ----------------
__global__ PIN11 void rec0(
    const float* __restrict__ z,       // [NB][NT]
    const float* __restrict__ l0w,     // [25][64][4]
    const float* __restrict__ l0b,     // [25][64][4]
    const f16* __restrict__ wfA0,
    float* __restrict__ hbufT)
{
  const int tid = threadIdx.x;
  const int w = tid >> 6, lane = tid & 63;
  const int bg = blockIdx.x;
  const int br = lane & 15, lg = lane >> 4;

  __shared__ f16 hHi[16][KP];
  __shared__ f16 hLo[16][KP];
  __shared__ float zl[NT][16];   // 32KB

  for (int i = tid; i < 16 * KP; i += 256) {
    int b = i / KP, k = i % KP;
    hHi[b][k] = (f16)0.0f;
    hLo[b][k] = (f16)0.0f;
  }
  for (int i = tid; i < 16 * NT; i += 256) {
    int j = i / NT, t = i % NT;
    zl[t][j] = z[(size_t)(bg * 16 + j) * NT + t];
  }

  f16x8 A[7][4];
  float c[7];
  f32x4 wv[7], bv[7];
#pragma unroll
  for (int s = 0; s < 7; ++s) {
    const int nt = s * 4 + w;
    c[s] = 0.0f;
    if (nt < NTILE) {
#pragma unroll
      for (int kt = 0; kt < 4; ++kt)
        A[s][kt] = *(const f16x8*)(wfA0 + ((nt * 4 + kt) * 64 + lane) * 8);
      wv[s] = *(const f32x4*)(l0w + (nt * 64 + lane) * 4);
      bv[s] = *(const f32x4*)(l0b + (nt * 64 + lane) * 4);
    }
  }
  __syncthreads();

  for (int t = 0; t < NT; ++t) {
    f16x8 Bhi[4], Blo[4];
#pragma unroll
    for (int kt = 0; kt < 4; ++kt) {
      Bhi[kt] = *(const f16x8*)(&hHi[br][kt * 32 + lg * 8]);
      Blo[kt] = *(const f16x8*)(&hLo[br][kt * 32 + lg * 8]);
    }
    const float zv = zl[t][br];
    f16 hhi[7], hlo[7];
#pragma unroll
    for (int s = 0; s < 7; ++s) {
      const int nt = s * 4 + w;
      if (nt < NTILE) {
        f32x4 acc = bv[s] + wv[s] * zv;
#pragma unroll
        for (int kt = 0; kt < 4; ++kt) {
          acc = __builtin_amdgcn_mfma_f32_16x16x32_f16(A[s][kt], Bhi[kt], acc, 0, 0, 0);
          acc = __builtin_amdgcn_mfma_f32_16x16x32_f16(A[s][kt], Blo[kt], acc, 0, 0, 0);
        }
        float iv = sigm(acc.x);
        float fv = sigm(acc.y);
        float gv = tanh_(acc.z);
        float ov = sigm(acc.w);
        c[s] = fv * c[s] + iv * gv;
        float hv = ov * tanh_(c[s]);
        f16 hi = (f16)hv;
        hhi[s] = hi;
        hlo[s] = (f16)(hv - (float)hi);
        const int u = nt * 4 + lg;
        hbufT[(((size_t)bg * NT + t) * HH + u) * 16 + br] = hv;
      }
    }
    __syncthreads();
#pragma unroll
    for (int s = 0; s < 7; ++s) {
      const int nt = s * 4 + w;
      if (nt < NTILE) {
        const int u = nt * 4 + lg;
        hHi[br][u] = hhi[s];
        hLo[br][u] = hlo[s];
      }
    }
    __syncthreads();
  }
}

// ---------------- projection ----------------
__global__ __launch_bounds__(256) void proj(
    const float* __restrict__ hbufT,
    const float* __restrict__ Wp, const float* __restrict__ bp,
    float* __restrict__ out)
{
  const int tid = threadIdx.x;
  const int bg = blockIdx.x >> 5, tsub = blockIdx.x & 31;
  const int br = tid & 15, tl = tid >> 4;
  const int t = tsub * 16 + tl;
  const float* hp = hbufT + (((size_t)bg * NT + t) * HH) * 16 + br;
  float acc = 0.0f;
#pragma unroll 4
  for (int u = 0; u < HH; ++u) acc += hp[u * 16] * Wp[u];
  out[(size_t)(bg * 16 + br) * NT + t] = tanh_(acc + bp[0]);
}

extern "C" void kernel_launch(void* const* d_in, const int* in_sizes, int n_in,
                              void* d_out, int out_size, void* d_ws, size_t ws_size,
                              hipStream_t stream) {
  const float* z    = (const float*)d_in[0];
  const float* Wih0 = (const float*)d_in[1];
  const float* Whh0 = (const float*)d_in[2];
  const float* b0   = (const float*)d_in[3];
  const float* Wih1 = (const float*)d_in[4];
  const float* Whh1 = (const float*)d_in[5];
  const float* b1   = (const float*)d_in[6];
  const float* Wih2 = (const float*)d_in[7];
  const float* Whh2 = (const float*)d_in[8];
  const float* b2   = (const float*)d_in[9];
  const float* Wp   = (const float*)d_in[10];
  const float* bp   = (const float*)d_in[11];
  float* out = (float*)d_out;

  float* ws = (float*)d_ws;
  float* hbufT = ws;                         // [32][512][100][16] = 26,214,400
  float* cbuf  = ws + 26214400;              // [32][25][64]       = 51,200
  f16*   wfA   = (f16*)(ws + 26265600);      // 153,600 halves (76,800 f32)
  f16*   wfI   = (f16*)(ws + 26342400);      // 102,400 halves (51,200 f32)
  float* biasf = ws + 26393600;              // 12,800
  float* l0w   = ws + 26406400;              // 6,400
  float* l0b   = ws + 26412800;              // 6,400
  float* xwf   = ws + 26419200;              // [32][CT][25][64][4]

  const size_t fixed = 26419200;
  int CT = 16;
  for (int c : {128, 64, 32, 16}) {
    if ((fixed + (size_t)NBG * c * 6400) * 4 <= ws_size) { CT = c; break; }
  }

  wprep<<<1100, 256, 0, stream>>>(Whh0, Whh1, Whh2, Wih1, Wih2, b1, b2,
                                  Wih0, b0, wfA, wfI, biasf, l0w, l0b);

  rec0<<<NBG, 256, 0, stream>>>(z, l0w, l0b, wfA, hbufT);

  for (int l = 0; l < 2; ++l) {
    const f16* wfAl = wfA + (size_t)(l + 1) * 51200;
    const f16* wfIl = wfI + (size_t)l * 51200;
    const float* bfl = biasf + (size_t)l * 6400;
    for (int t0 = 0; t0 < NT; t0 += CT) {
      xwp<<<NBG * (CT / 8), 512, 0, stream>>>(hbufT, wfIl, bfl, xwf, t0, CT);
      recx<<<NBG, 256, 0, stream>>>(xwf, wfAl, hbufT, cbuf, t0, CT);
    }
  }

  proj<<<1024, 256, 0, stream>>>(hbufT, Wp, bp, out);
}

// Round 12
// 3191.262 us; speedup vs baseline: 1.2963x; 1.1639x over previous
//
#include <hip/hip_runtime.h>
#include <cstdint>
#include <cstddef>

// LSTM_Generator: 3-layer LSTM (H=100) + tanh projection. B=512, T=512.
//
// R11 = R8 structure (best: 2700us; per-sequence blocks = full-GPU occupancy
// for the latency-bound recurrence) + v_dot2_f32_f16 to kill the AGPR spill:
//   - weights packed as 50 fp16 pairs -> 50 VGPRs (live set ~75 < 128 cliff)
//   - h split hi+lo fp16 pairs in LDS (R10-validated numerics, absmax 1.2e-4)
//   - 100 dot2 ops/step (same op count as fp32 FMA, half the registers,
//     no v_accvgpr_read tax)
//   - updater lanes pack h-pairs via __shfl_down(hv,4); no extra barrier
// xw_gemm (fp32 tiled, 87 TF measured), wprep, proj unchanged from R8.
// ws: hbuf[NB*NT*HH] | cbuf[NB*HH] | wt1[HH*448] | wt2 | bp1[448] | bp2 | xw[NB*CT*G4]

#define HH 100   // hidden
#define G4 400   // 4*H
#define NB 512   // batch
#define NT 512   // timesteps
#define WSTR 448 // padded gate dim for wT/bperm
#define MT 64    // GEMM M tile
#define NTL 64   // GEMM N tile
#define NNT 7    // ceil(400/64)

#define PIN44 __attribute__((amdgpu_flat_work_group_size(512, 512), \
                             amdgpu_waves_per_eu(4, 4)))
#define PIN22 __attribute__((amdgpu_flat_work_group_size(512, 512), \
                             amdgpu_waves_per_eu(2, 2)))

typedef _Float16 f16x2 __attribute__((ext_vector_type(2)));

__device__ __forceinline__ float sigm(float x) {
  return 1.0f / (1.0f + __expf(-x));
}
__device__ __forceinline__ float tanh_(float x) {
  return 1.0f - 2.0f / (__expf(2.0f * x) + 1.0f);
}
__device__ __forceinline__ float qb1(float v) {
  return __int_as_float(__builtin_amdgcn_ds_swizzle(__float_as_int(v), 0x8055));
}
__device__ __forceinline__ float qb2(float v) {
  return __int_as_float(__builtin_amdgcn_ds_swizzle(__float_as_int(v), 0x80AA));
}
__device__ __forceinline__ float qb3(float v) {
  return __int_as_float(__builtin_amdgcn_ds_swizzle(__float_as_int(v), 0x80FF));
}

__device__ __forceinline__ uint32_t packh2(float a, float b) {
  union { f16x2 h; uint32_t u; } c;
  c.h.x = (_Float16)a; c.h.y = (_Float16)b;
  return c.u;
}
__device__ __forceinline__ uint32_t packh2h(_Float16 a, _Float16 b) {
  union { f16x2 h; uint32_t u; } c;
  c.h.x = a; c.h.y = b;
  return c.u;
}
// fp16-pair dot with fp32 accumulate: D = a.x*b.x + a.y*b.y + c
__device__ __forceinline__ float fdot2(uint32_t a, uint32_t b, float c) {
#if __has_builtin(__builtin_amdgcn_fdot2)
  union { uint32_t u; f16x2 h; } ua, ub;
  ua.u = a; ub.u = b;
  return __builtin_amdgcn_fdot2(ua.h, ub.h, c, false);
#else
  float r;
  asm("v_dot2_f32_f16 %0, %1, %2, %3" : "=v"(r) : "v"(a), "v"(b), "v"(c));
  return r;
#endif
}

// ---------------- recurrent kernel (dot2, packed fp16 weights) ----------------
// MODE 0: xw precomputed (bias folded, quad-permuted), xsrc=[NB][tlen][G4]
// MODE 1: K=1 input, xsrc=z[NB][NT], Wih=[G4,1], bias added here
template <int MODE>
__global__ PIN44 void lstm_rec(
    const float* __restrict__ xsrc,
    const float* __restrict__ Wih,
    const float* __restrict__ Whh,
    const float* __restrict__ bias,
    float* __restrict__ hseq,        // [NB, NT, HH]
    float* __restrict__ cbuf,        // [NB, HH]
    int t0, int tlen)
{
  const int b = blockIdx.x;
  const int tid = threadIdx.x;

  // h as fp16 hi/lo pairs: 50 data pairs + 2 zero pads (13 uint4 reads)
  __shared__ __align__(16) uint32_t h_hi[2][52];
  __shared__ __align__(16) uint32_t h_lo[2][52];

  const bool isG = tid < G4;
  const int u = tid >> 2, g = tid & 3;     // quad map r=4u+g
  const int row = g * HH + u;

  uint32_t wp[50];                         // Whh row as 50 fp16 pairs
  float bb = 0.f, c = 0.f, wih1 = 0.f;
  if (isG) {
    const float4* w4 = reinterpret_cast<const float4*>(Whh + (size_t)row * HH);
#pragma unroll
    for (int k4 = 0; k4 < 25; ++k4) {
      float4 v = w4[k4];
      wp[2 * k4]     = packh2(v.x, v.y);
      wp[2 * k4 + 1] = packh2(v.z, v.w);
    }
    if constexpr (MODE == 1) {
      wih1 = Wih[row];
      bb = bias[row];
    }
  }

  // chunk init
  if (t0 == 0) {
    if (tid < 52) {
      h_hi[0][tid] = 0u; h_lo[0][tid] = 0u;
      h_hi[1][tid] = 0u; h_lo[1][tid] = 0u;
    }
  } else {
    if (tid < 52) {
      uint32_t ph = 0u, pl = 0u;
      if (tid < 50) {
        const float* hr = hseq + ((size_t)b * NT + (t0 - 1)) * HH + 2 * tid;
        float v0 = hr[0], v1 = hr[1];
        _Float16 h0 = (_Float16)v0, h1 = (_Float16)v1;
        ph = packh2h(h0, h1);
        pl = packh2(v0 - (float)h0, v1 - (float)h1);
      }
      h_hi[0][tid] = ph; h_lo[0][tid] = pl;
      h_hi[1][tid] = 0u; h_lo[1][tid] = 0u;   // pads; data rewritten each step
    }
    if (isG && g == 0) c = cbuf[b * HH + u];
  }

  // pointer-bump addressing
  const float* xq = xsrc + (size_t)b * tlen * G4 + tid;    // MODE 0
  const float* zp = xsrc + (size_t)b * NT + t0;            // MODE 1
  float* hp = hseq + ((size_t)b * NT + t0) * HH;

  float xa_n = 0.f, zc = 0.f;
  if constexpr (MODE == 0) {
    if (isG) xa_n = *xq;                   // prefetch step 0
  } else {
    zc = *zp;
  }
  __syncthreads();

  for (int s = 0; s < tlen; ++s) {
    const int cur = s & 1, nxt = cur ^ 1;

    float xa = 0.f, zn = 0.f;
    if constexpr (MODE == 0) {
      xa = xa_n;
      xq += (s + 1 < tlen) ? G4 : 0;
      if (isG) xa_n = *xq;                 // prefetch next step
    } else {
      zp += (s + 1 < tlen) ? 1 : 0;
      zn = *zp;
    }

    if (isG) {
      // 100 dot2 ops, 4 independent accumulate chains of 25
      float ac0 = xa, ac1 = 0.f, ac2 = 0.f, ac3 = 0.f;
#pragma unroll
      for (int q = 0; q < 13; ++q) {
        const uint4 Hh = *reinterpret_cast<const uint4*>(&h_hi[cur][4 * q]);
        const uint4 Hl = *reinterpret_cast<const uint4*>(&h_lo[cur][4 * q]);
        const int j0 = 4 * q;
        if (j0 + 0 < 50) { ac0 = fdot2(wp[j0 + 0], Hh.x, ac0); ac2 = fdot2(wp[j0 + 0], Hl.x, ac2); }
        if (j0 + 1 < 50) { ac1 = fdot2(wp[j0 + 1], Hh.y, ac1); ac3 = fdot2(wp[j0 + 1], Hl.y, ac3); }
        if (j0 + 2 < 50) { ac0 = fdot2(wp[j0 + 2], Hh.z, ac0); ac2 = fdot2(wp[j0 + 2], Hl.z, ac2); }
        if (j0 + 3 < 50) { ac1 = fdot2(wp[j0 + 3], Hh.w, ac1); ac3 = fdot2(wp[j0 + 3], Hl.w, ac3); }
      }
      float acc = (ac0 + ac1) + (ac2 + ac3);
      if constexpr (MODE == 1) acc += bb + wih1 * zc;
      float act = (g == 2) ? tanh_(acc) : sigm(acc);
      float fv = qb1(act);
      float gv = qb2(act);
      float ov = qb3(act);
      if (g == 0) {                        // lane 4u owns unit u's c,h
        c = fv * c + act * gv;
        float hv = ov * tanh_(c);
        hp[u] = hv;                        // f32 h to global (gemm/proj input)
        float hn = __shfl_down(hv, 4);     // partner unit u+1 (lane 4u+4)
        if ((u & 1) == 0) {                // even u packs pair (u, u+1)
          _Float16 h0 = (_Float16)hv, h1 = (_Float16)hn;
          h_hi[nxt][u >> 1] = packh2h(h0, h1);
          h_lo[nxt][u >> 1] = packh2(hv - (float)h0, hn - (float)h1);
        }
      }
    }
    hp += HH;
    if constexpr (MODE == 1) zc = zn;
    __syncthreads();
  }

  if (isG && g == 0) cbuf[b * HH + u] = c;
}

// ---------------- weight prep: wT[k][n] = Wih[perm(n)][k], bias permuted ----
__global__ __launch_bounds__(256) void wprep(
    const float* __restrict__ Wih,   // [G4, HH]
    const float* __restrict__ bias,  // [G4]
    float* __restrict__ wT,          // [HH, WSTR]
    float* __restrict__ bp)          // [WSTR]
{
  int idx = blockIdx.x * blockDim.x + threadIdx.x;
  if (idx >= HH * WSTR) return;
  int k = idx / WSTR, n = idx % WSTR;
  float v = 0.0f;
  if (n < G4) {
    int row = (n & 3) * HH + (n >> 2);      // quad map: n=4u+g -> row g*H+u
    v = Wih[(size_t)row * HH + k];
  }
  wT[idx] = v;
  if (idx < WSTR) bp[idx] = (idx < G4) ? bias[(idx & 3) * HH + (idx >> 2)] : 0.0f;
}

// ---------------- input GEMM: xw[b][t][n] = bperm[n] + h[b][t0+t][:].wT[:][n]
__global__ __launch_bounds__(256) void xw_gemm(
    const float* __restrict__ hsrc,  // [NB, NT, HH]
    const float* __restrict__ wT,    // [HH, WSTR]
    const float* __restrict__ bperm, // [WSTR]
    float* __restrict__ xw,          // [NB, CT, G4]
    int t0, int CT)
{
  const int mt = blockIdx.x / NNT, nt = blockIdx.x % NNT;
  const int m0 = mt * MT;
  const int b = m0 / CT, tr0 = m0 % CT;
  const int n0 = nt * NTL;
  const int tid = threadIdx.x;
  const int tx = tid & 15, ty = tid >> 4;

  __shared__ float Asub[HH][MT];
  __shared__ float Bsub[HH][NTL];

  for (int id = tid; id < MT * (HH / 4); id += 256) {
    const int k4 = id / MT, i = id % MT;
    const float4 v = *reinterpret_cast<const float4*>(
        hsrc + ((size_t)b * NT + (t0 + tr0 + i)) * HH + 4 * k4);
    Asub[4 * k4 + 0][i] = v.x;
    Asub[4 * k4 + 1][i] = v.y;
    Asub[4 * k4 + 2][i] = v.z;
    Asub[4 * k4 + 3][i] = v.w;
  }
  for (int id = tid; id < HH * (NTL / 4); id += 256) {
    const int k = id / (NTL / 4), q = id % (NTL / 4);
    const float4 v = *reinterpret_cast<const float4*>(wT + (size_t)k * WSTR + n0 + 4 * q);
    *reinterpret_cast<float4*>(&Bsub[k][4 * q]) = v;
  }
  __syncthreads();

  float acc[4][4] = {};
#pragma unroll 4
  for (int k = 0; k < HH; ++k) {
    const float4 a = *reinterpret_cast<const float4*>(&Asub[k][4 * ty]);
    const float4 bq = *reinterpret_cast<const float4*>(&Bsub[k][4 * tx]);
    acc[0][0] += a.x * bq.x; acc[0][1] += a.x * bq.y; acc[0][2] += a.x * bq.z; acc[0][3] += a.x * bq.w;
    acc[1][0] += a.y * bq.x; acc[1][1] += a.y * bq.y; acc[1][2] += a.y * bq.z; acc[1][3] += a.y * bq.w;
    acc[2][0] += a.z * bq.x; acc[2][1] += a.z * bq.y; acc[2][2] += a.z * bq.z; acc[2][3] += a.z * bq.w;
    acc[3][0] += a.w * bq.x; acc[3][1] += a.w * bq.y; acc[3][2] += a.w * bq.z; acc[3][3] += a.w * bq.w;
  }

  const int n = n0 + 4 * tx;
  if (n + 3 < G4) {
    const float4 bpq = *reinterpret_cast<const float4*>(bperm + n);
#pragma unroll
    for (int jr = 0; jr < 4; ++jr) {
      float4 o;
      o.x = acc[jr][0] + bpq.x; o.y = acc[jr][1] + bpq.y;
      o.z = acc[jr][2] + bpq.z; o.w = acc[jr][3] + bpq.w;
      *reinterpret_cast<float4*>(
          &xw[((size_t)b * CT + tr0 + 4 * ty + jr) * G4 + n]) = o;
    }
  }
}

// ---------------- fallback fused layer (only if ws too small) ----------------
__global__ PIN22 void lstm_fused(
    const float* x,
    const float* __restrict__ Wih,
    const float* __restrict__ Whh,
    const float* __restrict__ bias,
    float* hseq)
{
  const int b = blockIdx.x;
  const int tid = threadIdx.x;
  __shared__ __align__(16) float h_dbuf[2][HH];
  __shared__ __align__(16) float x_dbuf[2][HH];
  const bool isG = tid < G4;
  const int u = tid >> 2, g = tid & 3;
  const int row = g * HH + u;
  float whh[HH], wih[HH];
  float bb = 0.f, c = 0.f;
  if (isG) {
    const float4* wh4 = reinterpret_cast<const float4*>(Whh + (size_t)row * HH);
    const float4* wi4 = reinterpret_cast<const float4*>(Wih + (size_t)row * HH);
#pragma unroll
    for (int k = 0; k < HH / 4; ++k) {
      float4 a = wh4[k];
      whh[4 * k] = a.x; whh[4 * k + 1] = a.y; whh[4 * k + 2] = a.z; whh[4 * k + 3] = a.w;
      float4 bq = wi4[k];
      wih[4 * k] = bq.x; wih[4 * k + 1] = bq.y; wih[4 * k + 2] = bq.z; wih[4 * k + 3] = bq.w;
    }
    bb = bias[row];
  }
  if (tid < HH) h_dbuf[0][tid] = 0.0f;
  const float* xb = x + (size_t)b * NT * HH;
  float* hb = hseq + (size_t)b * NT * HH;
  const unsigned pf = (unsigned)(tid - 448);
  if (pf < 25u)
    reinterpret_cast<float4*>(x_dbuf[0])[pf] = reinterpret_cast<const float4*>(xb)[pf];
  __syncthreads();
  for (int t = 0; t < NT; ++t) {
    const int cur = t & 1, nxt = cur ^ 1;
    if (pf < 25u) {
      int tt = (t + 1 < NT) ? t + 1 : NT - 1;
      reinterpret_cast<float4*>(x_dbuf[nxt])[pf] =
          reinterpret_cast<const float4*>(xb + (size_t)tt * HH)[pf];
    }
    if (isG) {
      float a0 = 0.f, a1 = 0.f, a2 = 0.f, a3 = 0.f;
      const float4* x4 = reinterpret_cast<const float4*>(x_dbuf[cur]);
      const float4* h4 = reinterpret_cast<const float4*>(h_dbuf[cur]);
#pragma unroll
      for (int k = 0; k < HH / 4; ++k) {
        float4 v = x4[k];
        a0 += v.x * wih[4 * k];     a1 += v.y * wih[4 * k + 1];
        a2 += v.z * wih[4 * k + 2]; a3 += v.w * wih[4 * k + 3];
      }
#pragma unroll
      for (int k = 0; k < HH / 4; ++k) {
        float4 v = h4[k];
        a0 += v.x * whh[4 * k];     a1 += v.y * whh[4 * k + 1];
        a2 += v.z * whh[4 * k + 2]; a3 += v.w * whh[4 * k + 3];
      }
      float acc = bb + ((a0 + a1) + (a2 + a3));
      float act = (g == 2) ? tanh_(acc) : sigm(acc);
      float fv = qb1(act);
      float gv = qb2(act);
      float ov = qb3(act);
      if (g == 0) {
        c = fv * c + act * gv;
        float hv = ov * tanh_(c);
        h_dbuf[nxt][u] = hv;
        hb[(size_t)t * HH + u] = hv;
      }
    }
    __syncthreads();
  }
}

// ---------------- projection ----------------
__global__ __launch_bounds__(256) void proj_kernel(
    const float* __restrict__ hseq,
    const float* __restrict__ Wp,
    const float* __restrict__ bp,
    float* __restrict__ out)
{
  int idx = blockIdx.x * blockDim.x + threadIdx.x;
  if (idx >= NB * NT) return;
  const float4* h4 = reinterpret_cast<const float4*>(hseq + (size_t)idx * HH);
  const float4* w4 = reinterpret_cast<const float4*>(Wp);
  float a0 = 0.f, a1 = 0.f, a2 = 0.f, a3 = 0.f;
#pragma unroll
  for (int k = 0; k < HH / 4; ++k) {
    float4 h = h4[k];
    float4 w = w4[k];
    a0 += h.x * w.x; a1 += h.y * w.y; a2 += h.z * w.z; a3 += h.w * w.w;
  }
  out[idx] = tanh_(((a0 + a1) + (a2 + a3)) + bp[0]);
}

extern "C" void kernel_launch(void* const* d_in, const int* in_sizes, int n_in,
                              void* d_out, int out_size, void* d_ws, size_t ws_size,
                              hipStream_t stream) {
  const float* z    = (const float*)d_in[0];
  const float* Wih0 = (const float*)d_in[1];
  const float* Whh0 = (const float*)d_in[2];
  const float* b0   = (const float*)d_in[3];
  const float* Wih1 = (const float*)d_in[4];
  const float* Whh1 = (const float*)d_in[5];
  const float* b1   = (const float*)d_in[6];
  const float* Wih2 = (const float*)d_in[7];
  const float* Whh2 = (const float*)d_in[8];
  const float* b2   = (const float*)d_in[9];
  const float* Wp   = (const float*)d_in[10];
  const float* bp   = (const float*)d_in[11];
  float* out = (float*)d_out;

  float* hbuf = (float*)d_ws;                       // [NB,NT,HH]
  float* cbuf = hbuf + (size_t)NB * NT * HH;        // [NB,HH]
  float* wt1  = cbuf + (size_t)NB * HH;             // [HH,WSTR]
  float* wt2  = wt1 + (size_t)HH * WSTR;
  float* bp1  = wt2 + (size_t)HH * WSTR;            // [WSTR]
  float* bp2  = bp1 + WSTR;
  float* xwb  = bp2 + WSTR;                         // [NB,CT,G4]

  const size_t fixed = (size_t)(bp2 + WSTR - hbuf) * 4;
  int CT = 0;
  for (int c : {128, 64}) {
    if (fixed + (size_t)NB * c * G4 * 4 <= ws_size) { CT = c; break; }
  }

  // layer 0 (K=1): full-length
  lstm_rec<1><<<NB, 512, 0, stream>>>(z, Wih0, Whh0, b0, hbuf, cbuf, 0, NT);

  if (CT > 0) {
    wprep<<<(HH * WSTR + 255) / 256, 256, 0, stream>>>(Wih1, b1, wt1, bp1);
    wprep<<<(HH * WSTR + 255) / 256, 256, 0, stream>>>(Wih2, b2, wt2, bp2);
    const float* wtL[2] = {wt1, wt2};
    const float* bpL[2] = {bp1, bp2};
    const float* WhhL[2] = {Whh1, Whh2};
    const int gemm_grid = (NB * CT / MT) * NNT;
    for (int l = 0; l < 2; ++l) {
      for (int t0 = 0; t0 < NT; t0 += CT) {
        xw_gemm<<<gemm_grid, 256, 0, stream>>>(hbuf, wtL[l], bpL[l], xwb, t0, CT);
        lstm_rec<0><<<NB, 512, 0, stream>>>(xwb, nullptr, WhhL[l], nullptr,
                                            hbuf, cbuf, t0, CT);
      }
    }
  } else {
    lstm_fused<<<NB, 512, 0, stream>>>(hbuf, Wih1, Whh1, b1, hbuf);
    lstm_fused<<<NB, 512, 0, stream>>>(hbuf, Wih2, Whh2, b2, hbuf);
  }

  proj_kernel<<<(NB * NT + 255) / 256, 256, 0, stream>>>(hbuf, Wp, bp, out);
}

// Round 13
// 3042.271 us; speedup vs baseline: 1.3598x; 1.0490x over previous
//
#include <hip/hip_runtime.h>
#include <cstdint>
#include <cstddef>

// LSTM_Generator: 3-layer LSTM (H=100) + tanh projection. B=512, T=512.
//
// R12 = R10's MFMA design (validated: fragment maps, shared k-map, fp16-W +
// h hi/lo split, absmax 1.22e-4) with the schedule fixed:
//   - 512 thr / 8 waves: <=4 tile-slots per wave (was 4 waves x 7 serial)
//   - hi/lo MFMA chains independent (depth 8 -> 4), summed at the end
//   - h double-buffered in LDS -> ONE barrier per step (was 2)
//   - XOR-swizzled LDS (KP=128, 16B blocks, j^(br&7)): conflict-free b128
//     B-frag reads; buffers zero-initialized (NaN x 0 safety for k>=100)
//   - xw(t+1) register-prefetched across the barrier
// Per step per block: 25 tiles x 4kt x 2(hi/lo) = 200 mfma_f32_16x16x32_f16.
// Grid for rec kernels = 32 (structural: 16 batch/block); per-step latency is
// the lever, not occupancy.

#define HH 100
#define G4 400
#define NB 512
#define NT 512
#define NBG 32
#define NTILE 25
#define KP 128   // f16 per LDS row; 16B-block XOR swizzle

typedef _Float16 f16;
typedef _Float16 f16x8 __attribute__((ext_vector_type(8)));
typedef float f32x4 __attribute__((ext_vector_type(4)));

__device__ __forceinline__ float sigm(float x) { return 1.0f / (1.0f + __expf(-x)); }
__device__ __forceinline__ float tanh_(float x) { return 1.0f - 2.0f / (__expf(2.0f * x) + 1.0f); }

#define PIN22 __attribute__((amdgpu_flat_work_group_size(512, 512), \
                             amdgpu_waves_per_eu(2, 2)))

// swizzled f16 index in a [16][KP] buffer: batch row b2, element k=u
__device__ __forceinline__ int hswz(int b2, int u) {
  return b2 * KP + ((((u >> 3) ^ (b2 & 7)) << 3) | (u & 7));
}
// block read position: j = k/8
__device__ __forceinline__ int bswz(int b2, int j) {
  return b2 * KP + ((j ^ (b2 & 7)) << 3);
}

// ---------------- weight prep (verbatim R10, validated) ----------------
// Shared k-map (A and B): k = kt*32 + (lane>>4)*8 + j.
// A-frag: m' = nt*16 + (lane&15); orig row = (m'&3)*100 + (m'>>2).
// bias/l0 tables use C/D map: m' = nt*16 + (lane>>4)*4 + r.
__global__ __launch_bounds__(256) void wprep(
    const float* __restrict__ Whh0, const float* __restrict__ Whh1,
    const float* __restrict__ Whh2, const float* __restrict__ Wih1,
    const float* __restrict__ Wih2, const float* __restrict__ b1,
    const float* __restrict__ b2, const float* __restrict__ Wih0,
    const float* __restrict__ b0,
    f16* __restrict__ wfA, f16* __restrict__ wfI,
    float* __restrict__ biasf, float* __restrict__ l0w, float* __restrict__ l0b)
{
  int idx = blockIdx.x * 256 + threadIdx.x;
  if (idx < 153600) {                        // wfA [3][25][4][64][8]
    int l = idx / 51200, r = idx % 51200;
    int nt = r / 2048, r2 = r % 2048;
    int kt = r2 / 512, r3 = r2 % 512;
    int lane = r3 / 8, j = r3 % 8;
    int mp = nt * 16 + (lane & 15);
    int grow = (mp & 3) * HH + (mp >> 2);
    int k = kt * 32 + (lane >> 4) * 8 + j;
    const float* W = (l == 0) ? Whh0 : ((l == 1) ? Whh1 : Whh2);
    wfA[idx] = (k < HH) ? (f16)W[grow * HH + k] : (f16)0.0f;
    return;
  }
  idx -= 153600;
  if (idx < 102400) {                        // wfI [2][25][4][64][8]
    int l = idx / 51200, r = idx % 51200;
    int nt = r / 2048, r2 = r % 2048;
    int kt = r2 / 512, r3 = r2 % 512;
    int lane = r3 / 8, j = r3 % 8;
    int mp = nt * 16 + (lane & 15);
    int grow = (mp & 3) * HH + (mp >> 2);
    int k = kt * 32 + (lane >> 4) * 8 + j;
    const float* W = (l == 0) ? Wih1 : Wih2;
    wfI[idx] = (k < HH) ? (f16)W[grow * HH + k] : (f16)0.0f;
    return;
  }
  idx -= 102400;
  if (idx < 12800) {                         // biasf [2][25][64][4]
    int l = idx / 6400, r = idx % 6400;
    int nt = r / 256, r2 = r % 256;
    int lane = r2 / 4, rr = r2 % 4;
    int mp = nt * 16 + (lane >> 4) * 4 + rr;
    int grow = (mp & 3) * HH + (mp >> 2);
    biasf[idx] = ((l == 0) ? b1 : b2)[grow];
    return;
  }
  idx -= 12800;
  if (idx < 12800) {                         // l0w / l0b [25][64][4]
    int w = idx / 6400, r = idx % 6400;
    int nt = r / 256, r2 = r % 256;
    int lane = r2 / 4, rr = r2 % 4;
    int mp = nt * 16 + (lane >> 4) * 4 + rr;
    int grow = (mp & 3) * HH + (mp >> 2);
    if (w == 0) l0w[r] = Wih0[grow];
    else        l0b[r] = b0[grow];
  }
}

// ---------------- xw pass: xwf = bias + Wih . x^T (MFMA, parallel in t) ----
__global__ PIN22 void xwp(
    const float* __restrict__ hbufT,   // [bg][t][u][16]
    const f16* __restrict__ wfIl,      // [25][4][64][8]
    const float* __restrict__ biasl,   // [25][64][4]
    float* __restrict__ xwf,           // [bg][CT][25][64][4]
    int t0, int CT)
{
  const int tid = threadIdx.x;
  const int w = tid >> 6, lane = tid & 63;
  const int nblk = CT / 8;
  const int bg = blockIdx.x / nblk, ts = blockIdx.x % nblk;
  const int tb = t0 + ts * 8;
  const int br = lane & 15, lg = lane >> 4;

  __shared__ __align__(16) f16 x16[8][16 * KP];   // 32KB, swizzled

  {  // zero-init (NaN x 0 safety in pad blocks)
    uint32_t* p = (uint32_t*)&x16[0][0];
    for (int i = tid; i < 8 * 16 * KP / 2; i += 512) p[i] = 0u;
  }
  __syncthreads();
  for (int i = tid; i < 8 * HH * 16; i += 512) {
    int t = i / 1600, r = i % 1600;
    int u = r >> 4, b2 = r & 15;
    float v = hbufT[(((size_t)bg * NT + (tb + t)) * HH + u) * 16 + b2];
    x16[t][hswz(b2, u)] = (f16)v;
  }

  const int NS = (w == 7) ? 4 : 3;
  const int tbase = 3 * w;

  f16x8 A[4][4];
  f32x4 bias4[4];
#pragma unroll
  for (int s = 0; s < 4; ++s) {
    if (s < NS) {
      int nt = tbase + s;
#pragma unroll
      for (int kt = 0; kt < 4; ++kt)
        A[s][kt] = *(const f16x8*)(wfIl + ((nt * 4 + kt) * 64 + lane) * 8);
      bias4[s] = *(const f32x4*)(biasl + (nt * 64 + lane) * 4);
    }
  }
  __syncthreads();

  for (int t = 0; t < 8; ++t) {
    f16x8 B[4];
#pragma unroll
    for (int kt = 0; kt < 4; ++kt)
      B[kt] = *(const f16x8*)(&x16[t][bswz(br, (kt << 2) + lg)]);
    const int tc = ts * 8 + t;
#pragma unroll
    for (int s = 0; s < 4; ++s) {
      if (s < NS) {
        f32x4 acc = bias4[s];
#pragma unroll
        for (int kt = 0; kt < 4; ++kt)
          acc = __builtin_amdgcn_mfma_f32_16x16x32_f16(A[s][kt], B[kt], acc, 0, 0, 0);
        int nt = tbase + s;
        *(f32x4*)(xwf + ((((size_t)bg * CT + tc) * NTILE + nt) * 64 + lane) * 4) = acc;
      }
    }
  }
}

// ---------------- recurrent kernel, layers 1/2 (8 waves, 1 barrier/step) ----
__global__ PIN22 void recx(
    const float* __restrict__ xwf,
    const f16* __restrict__ wfAl,
    float* __restrict__ hbufT,
    float* __restrict__ cbuf,
    int t0, int CT)
{
  const int tid = threadIdx.x;
  const int w = tid >> 6, lane = tid & 63;
  const int bg = blockIdx.x;
  const int br = lane & 15, lg = lane >> 4;
  const int NS = (w == 0) ? 4 : 3;          // slots: nt = w + 8*s

  __shared__ __align__(16) f16 hHi[2][16 * KP];   // double-buffered, swizzled
  __shared__ __align__(16) f16 hLo[2][16 * KP];

  {  // zero-init both buffers
    uint32_t* p0 = (uint32_t*)&hHi[0][0];
    uint32_t* p1 = (uint32_t*)&hLo[0][0];
    for (int i = tid; i < 2 * 16 * KP / 2; i += 512) { p0[i] = 0u; p1[i] = 0u; }
  }
  __syncthreads();
  if (t0 > 0) {
    for (int i = tid; i < HH * 16; i += 512) {
      int u = i >> 4, b2 = i & 15;
      float v = hbufT[(((size_t)bg * NT + (t0 - 1)) * HH + u) * 16 + b2];
      f16 hi = (f16)v;
      hHi[0][hswz(b2, u)] = hi;
      hLo[0][hswz(b2, u)] = (f16)(v - (float)hi);
    }
  }

  f16x8 A[4][4];
  float c[4] = {0.f, 0.f, 0.f, 0.f};
  f32x4 xwC[4], xwN[4];
#pragma unroll
  for (int s = 0; s < 4; ++s) {
    if (s < NS) {
      const int nt = w + 8 * s;
#pragma unroll
      for (int kt = 0; kt < 4; ++kt)
        A[s][kt] = *(const f16x8*)(wfAl + ((nt * 4 + kt) * 64 + lane) * 8);
      if (t0 > 0) c[s] = cbuf[((size_t)bg * NTILE + nt) * 64 + lane];
      xwC[s] = *(const f32x4*)(xwf + (((size_t)bg * CT * NTILE + nt) * 64 + lane) * 4);
    }
  }
  __syncthreads();

  int cur = 0;
  for (int t = 0; t < CT; ++t) {
    f16x8 Bhi[4], Blo[4];
#pragma unroll
    for (int kt = 0; kt < 4; ++kt) {
      const int pos = bswz(br, (kt << 2) + lg);
      Bhi[kt] = *(const f16x8*)(&hHi[cur][pos]);
      Blo[kt] = *(const f16x8*)(&hLo[cur][pos]);
    }
    const int tn = (t + 1 < CT) ? t + 1 : t;   // prefetch next xw
#pragma unroll
    for (int s = 0; s < 4; ++s) {
      if (s < NS) {
        const int nt = w + 8 * s;
        xwN[s] = *(const f32x4*)(xwf + ((((size_t)bg * CT + tn) * NTILE + nt) * 64 + lane) * 4);
      }
    }
#pragma unroll
    for (int s = 0; s < 4; ++s) {
      if (s < NS) {
        const int nt = w + 8 * s;
        f32x4 ah = xwC[s];
        f32x4 al = {0.f, 0.f, 0.f, 0.f};
#pragma unroll
        for (int kt = 0; kt < 4; ++kt) {       // two independent 4-deep chains
          ah = __builtin_amdgcn_mfma_f32_16x16x32_f16(A[s][kt], Bhi[kt], ah, 0, 0, 0);
          al = __builtin_amdgcn_mfma_f32_16x16x32_f16(A[s][kt], Blo[kt], al, 0, 0, 0);
        }
        f32x4 acc = ah + al;
        float iv = sigm(acc.x);
        float fv = sigm(acc.y);
        float gv = tanh_(acc.z);
        float ov = sigm(acc.w);
        c[s] = fv * c[s] + iv * gv;
        float hv = ov * tanh_(c[s]);
        const int u = nt * 4 + lg;
        hbufT[(((size_t)bg * NT + (t0 + t)) * HH + u) * 16 + br] = hv;
        f16 hi = (f16)hv;
        hHi[cur ^ 1][hswz(br, u)] = hi;
        hLo[cur ^ 1][hswz(br, u)] = (f16)(hv - (float)hi);
      }
    }
    __syncthreads();
#pragma unroll
    for (int s = 0; s < 4; ++s) xwC[s] = xwN[s];
    cur ^= 1;
  }
#pragma unroll
  for (int s = 0; s < 4; ++s) {
    if (s < NS) {
      const int nt = w + 8 * s;
      cbuf[((size_t)bg * NTILE + nt) * 64 + lane] = c[s];
    }
  }
}

// ---------------- layer 0 (K=1 scalar input), full T ----------------
__global__ PIN22 void rec0(
    const float* __restrict__ z,       // [NB][NT]
    const float* __restrict__ l0w,     // [25][64][4]
    const float* __restrict__ l0b,     // [25][64][4]
    const f16* __restrict__ wfA0,
    float* __restrict__ hbufT)
{
  const int tid = threadIdx.x;
  const int w = tid >> 6, lane = tid & 63;
  const int bg = blockIdx.x;
  const int br = lane & 15, lg = lane >> 4;
  const int NS = (w == 0) ? 4 : 3;

  __shared__ __align__(16) f16 hHi[2][16 * KP];
  __shared__ __align__(16) f16 hLo[2][16 * KP];
  __shared__ __align__(16) float zl[NT][16];   // 32KB

  {
    uint32_t* p0 = (uint32_t*)&hHi[0][0];
    uint32_t* p1 = (uint32_t*)&hLo[0][0];
    for (int i = tid; i < 2 * 16 * KP / 2; i += 512) { p0[i] = 0u; p1[i] = 0u; }
  }
  for (int i = tid; i < 16 * NT; i += 512) {
    int j = i / NT, t = i % NT;
    zl[t][j] = z[(size_t)(bg * 16 + j) * NT + t];
  }

  f16x8 A[4][4];
  float c[4] = {0.f, 0.f, 0.f, 0.f};
  f32x4 wv[4], bv[4];
#pragma unroll
  for (int s = 0; s < 4; ++s) {
    if (s < NS) {
      const int nt = w + 8 * s;
#pragma unroll
      for (int kt = 0; kt < 4; ++kt)
        A[s][kt] = *(const f16x8*)(wfA0 + ((nt * 4 + kt) * 64 + lane) * 8);
      wv[s] = *(const f32x4*)(l0w + (nt * 64 + lane) * 4);
      bv[s] = *(const f32x4*)(l0b + (nt * 64 + lane) * 4);
    }
  }
  __syncthreads();

  int cur = 0;
  for (int t = 0; t < NT; ++t) {
    f16x8 Bhi[4], Blo[4];
#pragma unroll
    for (int kt = 0; kt < 4; ++kt) {
      const int pos = bswz(br, (kt << 2) + lg);
      Bhi[kt] = *(const f16x8*)(&hHi[cur][pos]);
      Blo[kt] = *(const f16x8*)(&hLo[cur][pos]);
    }
    const float zv = zl[t][br];
#pragma unroll
    for (int s = 0; s < 4; ++s) {
      if (s < NS) {
        const int nt = w + 8 * s;
        f32x4 ah = bv[s] + wv[s] * zv;
        f32x4 al = {0.f, 0.f, 0.f, 0.f};
#pragma unroll
        for (int kt = 0; kt < 4; ++kt) {
          ah = __builtin_amdgcn_mfma_f32_16x16x32_f16(A[s][kt], Bhi[kt], ah, 0, 0, 0);
          al = __builtin_amdgcn_mfma_f32_16x16x32_f16(A[s][kt], Blo[kt], al, 0, 0, 0);
        }
        f32x4 acc = ah + al;
        float iv = sigm(acc.x);
        float fv = sigm(acc.y);
        float gv = tanh_(acc.z);
        float ov = sigm(acc.w);
        c[s] = fv * c[s] + iv * gv;
        float hv = ov * tanh_(c[s]);
        const int u = nt * 4 + lg;
        hbufT[(((size_t)bg * NT + t) * HH + u) * 16 + br] = hv;
        f16 hi = (f16)hv;
        hHi[cur ^ 1][hswz(br, u)] = hi;
        hLo[cur ^ 1][hswz(br, u)] = (f16)(hv - (float)hi);
      }
    }
    __syncthreads();
    cur ^= 1;
  }
}

// ---------------- projection ----------------
__global__ __launch_bounds__(256) void proj(
    const float* __restrict__ hbufT,
    const float* __restrict__ Wp, const float* __restrict__ bp,
    float* __restrict__ out)
{
  const int tid = threadIdx.x;
  const int bg = blockIdx.x >> 5, tsub = blockIdx.x & 31;
  const int br = tid & 15, tl = tid >> 4;
  const int t = tsub * 16 + tl;
  const float* hp = hbufT + (((size_t)bg * NT + t) * HH) * 16 + br;
  float acc = 0.0f;
#pragma unroll 4
  for (int u = 0; u < HH; ++u) acc += hp[u * 16] * Wp[u];
  out[(size_t)(bg * 16 + br) * NT + t] = tanh_(acc + bp[0]);
}

extern "C" void kernel_launch(void* const* d_in, const int* in_sizes, int n_in,
                              void* d_out, int out_size, void* d_ws, size_t ws_size,
                              hipStream_t stream) {
  const float* z    = (const float*)d_in[0];
  const float* Wih0 = (const float*)d_in[1];
  const float* Whh0 = (const float*)d_in[2];
  const float* b0   = (const float*)d_in[3];
  const float* Wih1 = (const float*)d_in[4];
  const float* Whh1 = (const float*)d_in[5];
  const float* b1   = (const float*)d_in[6];
  const float* Wih2 = (const float*)d_in[7];
  const float* Whh2 = (const float*)d_in[8];
  const float* b2   = (const float*)d_in[9];
  const float* Wp   = (const float*)d_in[10];
  const float* bp   = (const float*)d_in[11];
  float* out = (float*)d_out;

  float* ws = (float*)d_ws;
  float* hbufT = ws;                         // [32][512][100][16] = 26,214,400
  float* cbuf  = ws + 26214400;              // [32][25][64]       = 51,200
  f16*   wfA   = (f16*)(ws + 26265600);      // 153,600 halves
  f16*   wfI   = (f16*)(ws + 26342400);      // 102,400 halves
  float* biasf = ws + 26393600;              // 12,800
  float* l0w   = ws + 26406400;              // 6,400
  float* l0b   = ws + 26412800;              // 6,400
  float* xwf   = ws + 26419200;              // [32][CT][25][64][4]

  const size_t fixed = 26419200;
  int CT = 16;
  for (int c : {128, 64, 32, 16}) {
    if ((fixed + (size_t)NBG * c * 6400) * 4 <= ws_size) { CT = c; break; }
  }

  wprep<<<1100, 256, 0, stream>>>(Whh0, Whh1, Whh2, Wih1, Wih2, b1, b2,
                                  Wih0, b0, wfA, wfI, biasf, l0w, l0b);

  rec0<<<NBG, 512, 0, stream>>>(z, l0w, l0b, wfA, hbufT);

  for (int l = 0; l < 2; ++l) {
    const f16* wfAl = wfA + (size_t)(l + 1) * 51200;
    const f16* wfIl = wfI + (size_t)l * 51200;
    const float* bfl = biasf + (size_t)l * 6400;
    for (int t0 = 0; t0 < NT; t0 += CT) {
      xwp<<<NBG * (CT / 8), 512, 0, stream>>>(hbufT, wfIl, bfl, xwf, t0, CT);
      recx<<<NBG, 512, 0, stream>>>(xwf, wfAl, hbufT, cbuf, t0, CT);
    }
  }

  proj<<<1024, 256, 0, stream>>>(hbufT, Wp, bp, out);
}